// Round 1
// 337.558 us; speedup vs baseline: 1.0282x; 1.0282x over previous
//
#include <hip/hip_runtime.h>

// Two-layer cached GCN. Round 7:
// (a) layer-1 hidden h stored as fp16 with relu pre-applied (exact: relu
//     commutes with rounding; gemm re-quantized to fp16 anyway) -> agg-1
//     write 50->25 MB, gemm-2 A-read 51->25.6 MB. h16 lives in front half
//     of d_out (overwritten by final fp32 out afterwards).
// (b) k_agg_csr: 16 lanes/row with 16B half8 gathers (half the vmem/VALU
//     instructions per edge, 4 rows in flight per wave), nontemporal out
//     stores + col loads (don't evict ts from L2).
// (c) k_gemm_mfma: A fragments loaded directly from global (A is read
//     exactly once; staging bought nothing), only W in LDS (34.8 KB) ->
//     4 blocks/CU, one barrier, no staging VALU.

#define BKT_SHIFT 7
#define BKT_NODES 128
#define CH 8192
#define MAXBKT 1024

typedef _Float16 half4v __attribute__((ext_vector_type(4)));
typedef _Float16 half8v __attribute__((ext_vector_type(8)));
typedef float float4v __attribute__((ext_vector_type(4)));

// ---------------- bucket histogram (LDS-privatized) ----------------
__global__ __launch_bounds__(256) void k_bincount(const int* __restrict__ dst,
                                                  int* __restrict__ bcnt, int E, int nbkt) {
    __shared__ int sh[MAXBKT];
    for (int i = threadIdx.x; i < nbkt; i += 256) sh[i] = 0;
    __syncthreads();
    for (long long e = (long long)blockIdx.x * 256 + threadIdx.x; e < E;
         e += (long long)gridDim.x * 256)
        atomicAdd(&sh[dst[e] >> BKT_SHIFT], 1);
    __syncthreads();
    for (int i = threadIdx.x; i < nbkt; i += 256)
        if (sh[i]) atomicAdd(&bcnt[i], sh[i]);
}

__global__ __launch_bounds__(1024) void k_bscan(const int* __restrict__ bcnt,
                                                int* __restrict__ bofs,
                                                int* __restrict__ bcur, int nbkt, int E) {
    __shared__ int sh[1024];
    int t = threadIdx.x;
    int v = (t < nbkt) ? bcnt[t] : 0;
    int x = v;
    sh[t] = x;
    __syncthreads();
    for (int o = 1; o < 1024; o <<= 1) {
        int y = (t >= o) ? sh[t - o] : 0;
        __syncthreads();
        x += y;
        sh[t] = x;
        __syncthreads();
    }
    if (t < nbkt) { bofs[t] = x - v; bcur[t] = x - v; }
    if (t == 0) bofs[nbkt] = E;
}

// bulk-reservation bin fill
__global__ __launch_bounds__(256) void k_binfill(const int* __restrict__ src,
                                                 const int* __restrict__ dst,
                                                 int* __restrict__ bcur,
                                                 unsigned* __restrict__ recs,
                                                 int E, int nbkt) {
    __shared__ unsigned stage[CH];          // 32 KB
    __shared__ unsigned short stageb[CH];   // 16 KB
    __shared__ int cnt[MAXBKT];             // 4 KB
    __shared__ int base[MAXBKT];            // 4 KB
    const int t = threadIdx.x;
    const long long c0 = (long long)blockIdx.x * CH;

    for (int i = t; i < nbkt; i += 256) cnt[i] = 0;
    __syncthreads();

    for (int k = 0; k < CH / 256; k++) {
        int i = k * 256 + t;
        long long e = c0 + i;
        if (e < E) {
            int d = dst[e];
            int b = d >> BKT_SHIFT;
            stage[i] = ((unsigned)(d & (BKT_NODES - 1)) << 17) | (unsigned)src[e];
            stageb[i] = (unsigned short)b;
            atomicAdd(&cnt[b], 1);
        }
    }
    __syncthreads();

    for (int i = t; i < nbkt; i += 256) {
        int c = cnt[i];
        base[i] = c ? atomicAdd(&bcur[i], c) : 0;
        cnt[i] = 0;
    }
    __syncthreads();

    for (int k = 0; k < CH / 256; k++) {
        int i = k * 256 + t;
        if (c0 + i < E) {
            int b = stageb[i];
            int p = base[b] + atomicAdd(&cnt[b], 1);
            recs[p] = stage[i];
        }
    }
}

__global__ __launch_bounds__(256) void k_deg_bins(const unsigned* __restrict__ recs,
                                                  const int* __restrict__ bofs,
                                                  int* __restrict__ deg, int n) {
    __shared__ int cnt[BKT_NODES];
    const int b = blockIdx.x, t = threadIdx.x;
    if (t < BKT_NODES) cnt[t] = 0;
    __syncthreads();
    const int beg = bofs[b], end = bofs[b + 1];
    for (int j = beg + t; j < end; j += 256)
        atomicAdd(&cnt[recs[j] >> 17], 1);
    __syncthreads();
    const int d0 = b << BKT_SHIFT;
    if (t < BKT_NODES && d0 + t < n) deg[d0 + t] = cnt[t];
}

__global__ void k_scan1(const int* __restrict__ deg, float* __restrict__ dinv,
                        int* __restrict__ ofs, int* __restrict__ sums, int n) {
    __shared__ int sh[256];
    const int t = threadIdx.x;
    const int i = blockIdx.x * 256 + t;
    int v = (i < n) ? deg[i] : 0;
    if (i < n) dinv[i] = rsqrtf((float)v + 1.0f);
    int x = v;
    sh[t] = x;
    __syncthreads();
    for (int o = 1; o < 256; o <<= 1) {
        int y = (t >= o) ? sh[t - o] : 0;
        __syncthreads();
        x += y;
        sh[t] = x;
        __syncthreads();
    }
    if (i < n) ofs[i] = x - v;
    if (t == 255) sums[blockIdx.x] = x;
}

__global__ void k_scan2(int* __restrict__ sums, int nb) {
    __shared__ int sh[512];
    const int t = threadIdx.x;
    int carry = 0;
    for (int base = 0; base < nb; base += 512) {
        int i = base + t;
        int v = (i < nb) ? sums[i] : 0;
        int x = v;
        sh[t] = x;
        __syncthreads();
        for (int o = 1; o < 512; o <<= 1) {
            int y = (t >= o) ? sh[t - o] : 0;
            __syncthreads();
            x += y;
            sh[t] = x;
            __syncthreads();
        }
        if (i < nb) sums[i] = x - v + carry;
        int tot = sh[511];
        __syncthreads();
        carry += tot;
    }
}

__global__ void k_scan3(int* __restrict__ ofs, const int* __restrict__ sums, int n, int E) {
    int i = blockIdx.x * 256 + threadIdx.x;
    if (i < n) ofs[i] += sums[blockIdx.x];
    if (i == 0) ofs[n] = E;
}

__global__ __launch_bounds__(256) void k_fill_bins(const unsigned* __restrict__ recs,
                                                   const int* __restrict__ bofs,
                                                   const int* __restrict__ ofs,
                                                   int* __restrict__ col, int n) {
    __shared__ int cur[BKT_NODES];
    const int b = blockIdx.x, t = threadIdx.x;
    const int d0 = b << BKT_SHIFT;
    if (t < BKT_NODES) cur[t] = (d0 + t < n) ? ofs[d0 + t] : 0;
    __syncthreads();
    const int beg = bofs[b], end = bofs[b + 1];
    for (int j = beg + t; j < end; j += 256) {
        unsigned r = recs[j];
        int p = atomicAdd(&cur[r >> 17], 1);
        col[p] = (int)(r & 0x1FFFF);
    }
}

// ---------------- W -> fp16 transposed: Wt[n][k] = W[k][n] ----------------
__global__ __launch_bounds__(256) void k_wt(const float* __restrict__ W,
                                            _Float16* __restrict__ Wt) {
    int i = blockIdx.x * 256 + threadIdx.x;   // 16384
    int k = i >> 7, c = i & 127;
    Wt[c * 128 + k] = (_Float16)W[k * 128 + c];
}

// ---------------- MFMA GEMM: ts[N x 128](fp16) = dinv[row] * (in @ W) ----------------
// 64 rows/block, 4 waves, each wave: 16 rows x 128 cols via 8 16x16 tiles,
// K=128 in 4 chunks of 32. A fragments come straight from global (each A
// element is consumed exactly once; per-quad lanes cover contiguous 128B
// row chunks so the wave reads 16 full cache-line chunks per kc). Only W
// lives in LDS (padded rows -> conflict-free fragment reads); 4 blocks/CU.
template <int IN_HALF>
__global__ __launch_bounds__(256, 4) void k_gemm_mfma(const void* __restrict__ inp,
                                                      const _Float16* __restrict__ Wt,
                                                      const float* __restrict__ dinv,
                                                      _Float16* __restrict__ out, int n) {
    __shared__ _Float16 Bl[128][136];  // 34.8 KB
    const int t = threadIdx.x;
    const int row0 = blockIdx.x * 64;

    // stage Wt (fp16, already [n][k]) via 16B loads
    for (int i = t; i < 128 * 16; i += 256) {
        int r = i >> 4, c8 = i & 15;
        *(half8v*)&Bl[r][c8 * 8] = *(const half8v*)&Wt[r * 128 + c8 * 8];
    }
    __syncthreads();

    const int wave = t >> 6;        // 0..3 -> 16-row strip
    const int lane = t & 63;
    const int m0 = wave * 16;
    const int ml = lane & 15;       // m (A) / n (B) / col (D) within tile
    const int quad = lane >> 4;     // k-octet selector; D row group

    int r = row0 + m0 + ml;
    if (r >= n) r = n - 1;          // clamp: OOB rows compute garbage, never stored

    float4v acc[8] = {};
#pragma unroll
    for (int kc = 0; kc < 4; kc++) {
        half8v a;
        if (IN_HALF) {
            a = *(const half8v*)((const _Float16*)inp + (size_t)r * 128 + kc * 32 + quad * 8);
        } else {
            const float* ap = (const float*)inp + (size_t)r * 128 + kc * 32 + quad * 8;
            float4v v0 = *(const float4v*)ap;
            float4v v1 = *(const float4v*)(ap + 4);
#pragma unroll
            for (int k = 0; k < 4; k++) {
                a[k] = (_Float16)v0[k];
                a[4 + k] = (_Float16)v1[k];
            }
        }
#pragma unroll
        for (int nt = 0; nt < 8; nt++) {
            half8v b = *(const half8v*)&Bl[nt * 16 + ml][kc * 32 + quad * 8];
            acc[nt] = __builtin_amdgcn_mfma_f32_16x16x32_f16(a, b, acc[nt], 0, 0, 0);
        }
    }

    int nr = n - row0;
    if (nr > 64) nr = 64;
    // D: col = ml, row = quad*4 + reg
#pragma unroll
    for (int reg = 0; reg < 4; reg++) {
        int rr = m0 + quad * 4 + reg;
        if (rr < nr) {
            float dv = dinv[row0 + rr];
#pragma unroll
            for (int nt = 0; nt < 8; nt++)
                out[(size_t)(row0 + rr) * 128 + nt * 16 + ml] =
                    (_Float16)(acc[nt][reg] * dv);
        }
    }
}

// ---------------- CSR aggregation ----------------
// 16 lanes per row, 16B half8 gathers (half the vmem/VALU instr per edge vs
// 32x8B). OUT_HALF=1: store relu(bias + dinv*acc) as fp16 (layer-1 hidden:
// exact vs fp32-then-cast since gemm re-quantizes anyway and relu commutes
// with rounding). Nontemporal out/col so the streams don't evict ts from L2.
template <int OUT_HALF>
__global__ __launch_bounds__(256) void k_agg_csr(const int* __restrict__ ofs,
                                                 const int* __restrict__ col,
                                                 const float* __restrict__ dinv,
                                                 const half8v* __restrict__ ts,  // rows of 16 half8
                                                 const float* __restrict__ bias,
                                                 void* __restrict__ outp, int n) {
    int gid = blockIdx.x * 256 + threadIdx.x;
    int row = gid >> 4;
    int lane = gid & 15;
    if (row >= n) return;

    float dd = dinv[row];
    int beg = ofs[row];
    int end = ofs[row + 1];

    half8v sv = ts[(size_t)row * 16 + lane];
    float acc[8];
#pragma unroll
    for (int k = 0; k < 8; k++) acc[k] = (float)sv[k];

    int j = beg;
    for (; j + 3 < end; j += 4) {
        int s0 = __builtin_nontemporal_load(&col[j]);
        int s1 = __builtin_nontemporal_load(&col[j + 1]);
        int s2 = __builtin_nontemporal_load(&col[j + 2]);
        int s3 = __builtin_nontemporal_load(&col[j + 3]);
        half8v v0 = ts[(size_t)s0 * 16 + lane];
        half8v v1 = ts[(size_t)s1 * 16 + lane];
        half8v v2 = ts[(size_t)s2 * 16 + lane];
        half8v v3 = ts[(size_t)s3 * 16 + lane];
#pragma unroll
        for (int k = 0; k < 8; k++)
            acc[k] += (float)v0[k] + (float)v1[k] + (float)v2[k] + (float)v3[k];
    }
    for (; j < end; j++) {
        half8v v = ts[(size_t)__builtin_nontemporal_load(&col[j]) * 16 + lane];
#pragma unroll
        for (int k = 0; k < 8; k++) acc[k] += (float)v[k];
    }

    float4v bv0 = *(const float4v*)&bias[lane * 8];
    float4v bv1 = *(const float4v*)&bias[lane * 8 + 4];

    if (OUT_HALF) {
        half8v hv;
#pragma unroll
        for (int k = 0; k < 4; k++) {
            hv[k] = (_Float16)fmaxf(bv0[k] + dd * acc[k], 0.f);
            hv[4 + k] = (_Float16)fmaxf(bv1[k] + dd * acc[4 + k], 0.f);
        }
        __builtin_nontemporal_store(hv, &((half8v*)outp)[(size_t)row * 16 + lane]);
    } else {
        float4v o0, o1;
#pragma unroll
        for (int k = 0; k < 4; k++) {
            o0[k] = bv0[k] + dd * acc[k];
            o1[k] = bv1[k] + dd * acc[4 + k];
        }
        float* op = (float*)outp + (size_t)row * 128 + lane * 8;
        __builtin_nontemporal_store(o0, (float4v*)op);
        __builtin_nontemporal_store(o1, (float4v*)(op + 4));
    }
}

extern "C" void kernel_launch(void* const* d_in, const int* in_sizes, int n_in,
                              void* d_out, int out_size, void* d_ws, size_t ws_size,
                              hipStream_t stream) {
    const int N = in_sizes[0] / 128;
    const int E = in_sizes[1] / 2;
    const float* x  = (const float*)d_in[0];
    const int*   ei = (const int*)d_in[1];
    const float* W1 = (const float*)d_in[2];
    const float* b1 = (const float*)d_in[3];
    const float* W2 = (const float*)d_in[4];
    const float* b2 = (const float*)d_in[5];

    const int* src = ei;
    const int* dst = ei + E;

    const int nb_n  = (N + 255) / 256;
    const int NBKT  = (N + BKT_NODES - 1) / BKT_NODES;

    // ---- workspace layout (16B-aligned fp16 blocks first) ----
    _Float16* t    = (_Float16*)d_ws;            // N*128
    _Float16* wt1  = t + (size_t)N * 128;        // 16384
    _Float16* wt2  = wt1 + 16384;                // 16384
    float*    dinv = (float*)(wt2 + 16384);      // N
    int*      ofs  = (int*)(dinv + N);           // N+1
    int*      deg  = ofs + N + 1;                // N
    int*      sums = deg + N;                    // nb_n (padded)
    unsigned* recs = (unsigned*)(sums + ((nb_n + 255) & ~255)); // E
    int*      col  = (int*)(recs + E);           // E
    int*      bofs = col + E;                    // NBKT+1
    int*      bcur = bofs + NBKT + 1;            // NBKT
    int*      bcnt = bcur + NBKT;                // NBKT

    // layer-1 hidden (fp16, relu applied) in front half of d_out;
    // final fp32 out overwrites all of d_out afterwards.
    _Float16* h16 = (_Float16*)d_out;
    float*    out = (float*)d_out;

    const int nb_g = (N + 63) / 64;
    const int nb_a = (int)(((long long)N * 16 + 255) / 256);
    const int nb_c = (int)(((long long)E + CH - 1) / CH);

    // ---- weight prep + binning + CSR build (reused by both layers) ----
    k_wt<<<64, 256, 0, stream>>>(W1, wt1);
    k_wt<<<64, 256, 0, stream>>>(W2, wt2);
    hipMemsetAsync(bcnt, 0, (size_t)NBKT * 4, stream);
    k_bincount<<<256, 256, 0, stream>>>(dst, bcnt, E, NBKT);
    k_bscan<<<1, 1024, 0, stream>>>(bcnt, bofs, bcur, NBKT, E);
    k_binfill<<<nb_c, 256, 0, stream>>>(src, dst, bcur, recs, E, NBKT);
    k_deg_bins<<<NBKT, 256, 0, stream>>>(recs, bofs, deg, N);
    k_scan1<<<nb_n, 256, 0, stream>>>(deg, dinv, ofs, sums, N);
    k_scan2<<<1, 512, 0, stream>>>(sums, nb_n);
    k_scan3<<<nb_n, 256, 0, stream>>>(ofs, sums, N, E);
    k_fill_bins<<<NBKT, 256, 0, stream>>>(recs, bofs, ofs, col, N);

    // ---- layer 1: ts = dinv*(x@W1); h16 = relu(b1 + dinv*(ts[d] + sum ts[col])) ----
    k_gemm_mfma<0><<<nb_g, 256, 0, stream>>>(x, wt1, dinv, t, N);
    k_agg_csr<1><<<nb_a, 256, 0, stream>>>(ofs, col, dinv, (const half8v*)t, b1, h16, N);

    // ---- layer 2: ts = dinv*(h16@W2); out = b2 + dinv*(ts[d] + sum ts[col]) ----
    k_gemm_mfma<1><<<nb_g, 256, 0, stream>>>(h16, wt2, dinv, t, N);
    k_agg_csr<0><<<nb_a, 256, 0, stream>>>(ofs, col, dinv, (const half8v*)t, b2, out, N);
}